// Round 26
// baseline (57.952 us; speedup 1.0000x reference)
//
#include <hip/hip_runtime.h>
#include <hip/hip_bf16.h>
#include <math.h>

#define DM    1024
#define DH    64
#define NCTX  4096
#define NCH   8        // key-chunks per q-group

typedef __attribute__((ext_vector_type(8))) _Float16 f16x8;
typedef __attribute__((ext_vector_type(4))) float f32x4;

// ---- d_out scratch (16 MiB): written by wsplit/proj, consumed by proj/attn;
// the final kernel reads ONLY d_ws and overwrites d_out (race-free).
#define D_QH   0
#define D_QM   524288
#define D_KH   1572864
#define D_KM   2097152
#define D_UTB  3145728
#define D_PY   3670016    // fallback-path partials live here
#define D_PM   12058624
#define D_PL   12189696
#define D_WTH  12320768
#define D_WTM  12713984   // end 13107200

// ---- d_ws layout. WvT digits always at 0. Primary path (ws >= 8.5 MiB):
// partials in ws -> fused combine+out reads only ws.
#define S_WVH  0          // 128 KiB fp16 WvT^t high [1024][64]
#define S_WVM  131072     // 128 KiB
#define S_PM   262144     // 128 KiB f32 [NCH][NCTX]
#define S_PL   393216     // 128 KiB
#define S_PY   524288     // 8 MiB f32 [NCH][NCTX][DH]
#define S_END  8912896
// Fallback path: Y digit arrays in ws
#define S_YH   262144     // 512 KiB
#define S_YM   786432     // 512 KiB (end 1310720 < 4456448 proven)

__device__ __forceinline__ ushort f2h(float x) {
  _Float16 h = (_Float16)x;
  return __builtin_bit_cast(ushort, h);
}
__device__ __forceinline__ float h2f(ushort u) {
  return (float)__builtin_bit_cast(_Float16, u);
}

// async global->LDS, 16B/lane: LDS dest wave-uniform base + lane*16;
// global src per-lane (pre-swizzled source, linear LDS dest -- rule #21).
typedef __attribute__((address_space(1))) const unsigned int gas_u32;
typedef __attribute__((address_space(3))) unsigned int las_u32;
__device__ __forceinline__ void gload_lds16(const void* g, void* l) {
  __builtin_amdgcn_global_load_lds((gas_u32*)g, (las_u32*)l, 16, 0, 0);
}

// ---------------- W -> WT fp16 2-digit split (r22-validated) ----------
__global__ __launch_bounds__(256) void wsplit_kernel(
    const float* __restrict__ Wq, const float* __restrict__ WkT,
    const float* __restrict__ Wo, const float* __restrict__ Wv,
    ushort* __restrict__ WTh, ushort* __restrict__ WTm,
    ushort* __restrict__ WvTh, ushort* __restrict__ WvTm)
{
  int gid = blockIdx.x * 256 + threadIdx.x;
  int mat = gid >> 16;
  int idx = gid & 65535;
  if (mat == 3) {
    float v = Wv[idx];                 // Wv[h][c], coalesced read
    int h = idx >> 10, c = idx & 1023;
    int oidx = c * 64 + h;             // WvT^t[c][h]
    ushort h16 = f2h(v);
    WvTh[oidx] = h16;
    WvTm[oidx] = f2h(v - h2f(h16));
    return;
  }
  float v; int oidx;
  if (mat == 1) {
    v = WkT[idx];
    oidx = 65536 + idx;
  } else {
    int k = idx >> 6, h = idx & 63;
    v = (mat == 0 ? Wq : Wo)[idx];
    oidx = mat * 65536 + h * 1024 + k;
  }
  ushort h16 = f2h(v);
  float rem = v - h2f(h16);
  WTh[oidx] = h16;
  WTm[oidx] = f2h(rem);
}

// ---------------- projections via MFMA: fp16 2-digit, 3 products ----------------
// Grid (256, 3): 16-row blocks -> 3.0 blocks/CU of work (balance fix; per-output
// math identical to the r25-validated kernel -- same k-order and products).
// Wave w owns col-tile w (16 cols); all waves share the 16 x-rows.
__global__ __launch_bounds__(256, 2) void proj_mfma_kernel(
    const float* __restrict__ x,
    const ushort* __restrict__ WTh, const ushort* __restrict__ WTm,
    ushort* __restrict__ Qh, ushort* __restrict__ Qm,
    ushort* __restrict__ Kh, ushort* __restrict__ Km,
    ushort* __restrict__ UTb)
{
  __shared__ __align__(16) ushort xsh[16*128], xsm[16*128];        // 4 KiB each
  __shared__ __align__(16) ushort wsh[2][64*128], wsm[2][64*128];  // 16 KiB each buf

  const int tid  = threadIdx.x;
  const int lane = tid & 63;
  const int w    = tid >> 6;
  const int q16  = lane & 15;
  const int grp  = lane >> 4;
  const int r0   = blockIdx.x * 16;
  const int mat  = blockIdx.y;
  const ushort* __restrict__ wh = WTh + mat * 65536;
  const ushort* __restrict__ wm = WTm + mat * 65536;

  const int ct0 = w;                     // wave's col-tile

  const int xrowl = tid >> 4, xslot = tid & 15;   // 1 staging unit/thread

  auto stage_w = [&](int b, int s) {
    const int kp0 = s * 128;
    #pragma unroll
    for (int u = 0; u < 4; ++u) {
      int ubase = u * 256 + w * 64;
      int unit  = ubase + lane;
      int row   = unit >> 4, slotp = unit & 15;
      int ssrc  = slotp ^ (row & 15);
      int gsrc  = row * DM + kp0 + ssrc * 8;
      gload_lds16(&wh[gsrc], &wsh[b][ubase * 8]);
      gload_lds16(&wm[gsrc], &wsm[b][ubase * 8]);
    }
  };
  auto xload = [&](int s, float4& a0, float4& a1) {
    const int kp0 = s * 128;
    const float* s0 = &x[(r0 + xrowl) * DM + kp0 + xslot * 8];
    a0 = *(const float4*)&s0[0]; a1 = *(const float4*)&s0[4];
  };
  auto xsplit_write = [&](float4 a0, float4 a1) {
    float xv0[8] = {a0.x,a0.y,a0.z,a0.w,a1.x,a1.y,a1.z,a1.w};
    ushort hv0[8], mv0[8];
    #pragma unroll
    for (int e = 0; e < 8; ++e) {
      ushort h0 = f2h(xv0[e]);
      hv0[e] = h0;  mv0[e] = f2h(xv0[e] - h2f(h0));
    }
    int d0 = xrowl * 128 + ((xslot ^ (xrowl & 15)) << 3);
    #pragma unroll
    for (int e = 0; e < 8; ++e) {
      xsh[d0+e] = hv0[e]; xsm[d0+e] = mv0[e];
    }
  };

  f32x4 acc = {0,0,0,0};

  {
    float4 a0, a1;
    xload(0, a0, a1);
    xsplit_write(a0, a1);
    stage_w(0, 0);
  }
  __syncthreads();

  int cur = 0;
  for (int stg = 0; stg < 8; ++stg) {
    float4 na0, na1;
    if (stg < 7) {
      xload(stg + 1, na0, na1);
      stage_w(cur ^ 1, stg + 1);
    }
    #pragma unroll
    for (int ksub = 0; ksub < 4; ++ksub) {
      const int s = ksub * 4 + grp;
      const int xrow = q16;
      f16x8 xh8 = *(const f16x8*)&xsh[xrow * 128 + ((s ^ (xrow & 15)) << 3)];
      f16x8 xm8 = *(const f16x8*)&xsm[xrow * 128 + ((s ^ (xrow & 15)) << 3)];
      const int wrow = ct0 * 16 + q16;
      const int woff = wrow * 128 + ((s ^ (wrow & 15)) << 3);
      f16x8 bh = *(const f16x8*)&wsh[cur][woff];
      f16x8 bm = *(const f16x8*)&wsm[cur][woff];
      if (mat == 2) {   // A = W, B = x (validated operand pattern)
        acc = __builtin_amdgcn_mfma_f32_16x16x32_f16(bh, xh8, acc, 0,0,0);
        acc = __builtin_amdgcn_mfma_f32_16x16x32_f16(bh, xm8, acc, 0,0,0);
        acc = __builtin_amdgcn_mfma_f32_16x16x32_f16(bm, xh8, acc, 0,0,0);
      } else {          // A = x, B = W
        acc = __builtin_amdgcn_mfma_f32_16x16x32_f16(xh8, bh, acc, 0,0,0);
        acc = __builtin_amdgcn_mfma_f32_16x16x32_f16(xh8, bm, acc, 0,0,0);
        acc = __builtin_amdgcn_mfma_f32_16x16x32_f16(xm8, bh, acc, 0,0,0);
      }
    }
    __syncthreads();
    if (stg < 7) xsplit_write(na0, na1);
    __syncthreads();
    cur ^= 1;
  }

  if (mat == 2) {
    // D[wcol = ct0*16+4grp+r][xrow = r0+q16]
    #pragma unroll
    for (int r = 0; r < 4; ++r)
      UTb[(ct0*16 + 4*grp + r) * NCTX + r0 + q16] = f2h(acc[r]);
  } else {
    ushort* __restrict__ Dh = (mat == 0) ? Qh : Kh;
    ushort* __restrict__ Dm = (mat == 0) ? Qm : Km;
    // D[xrow = r0+4grp+r][wcol = ct0*16+q16]
    #pragma unroll
    for (int r = 0; r < 4; ++r) {
      float v = acc[r];
      ushort h = f2h(v);
      ushort m = f2h(v - h2f(h));
      int idx = (r0 + 4*grp + r) * DH + ct0*16 + q16;
      Dh[idx] = h; Dm[idx] = m;
    }
  }
}

// ---------------- MFMA flash attention: fp16 2-digit scores (r25-validated) -----
__global__ __launch_bounds__(256, 2) void attn_kernel(
    const ushort* __restrict__ Qh, const ushort* __restrict__ Qm,
    const ushort* __restrict__ Kh, const ushort* __restrict__ Km,
    const ushort* __restrict__ UTb,
    float* __restrict__ Pm, float* __restrict__ Pl, float* __restrict__ Py)
{
  __shared__ ushort Ksh[2][2][64*64];              // 32 KiB
  __shared__ ushort Ush[2][64*64];                 // 16 KiB
  __shared__ __align__(16) ushort ps[4][16*72];    //  9 KiB

  const int tid  = threadIdx.x;
  const int lane = tid & 63;
  const int w    = tid >> 6;
  ushort* psw = ps[w];
  const int q16  = lane & 15;
  const int grp  = lane >> 4;
  const int colb = grp * 8;

  const int bid = blockIdx.x;           // 0..511
  const int j   = bid & 255;
  const int hi  = bid >> 8;
  const int qq  = hi ? (63 - (j & 63)) : (j & 63);
  const int c   = (j >> 6) + hi * 4;    // bijective onto (qq, c) pairs

  const int gbase = 252 - 4 * qq;
  const int g     = gbase + w;
  const int gmax  = gbase + 3;
  const int T     = ((16*gmax + 15) >> 6) + 1;
  const int t0 = (c * T) >> 3, t1 = ((c+1) * T) >> 3;
  const int Town = ((16*g + 15) >> 6) + 1;
  const int q0 = 16 * g;
  const int q  = q0 + q16;

  auto stage = [&](int b, int t) {
    const int j0 = t * 64;
    #pragma unroll
    for (int it = 0; it < 2; ++it) {
      int ubase = it * 256 + w * 64;
      int unit  = ubase + lane;
      int row   = unit >> 3, slotp = unit & 7;
      int c8    = slotp ^ (row & 7);
      int src   = (j0 + row) * DH + c8 * 8;
      gload_lds16(&Kh[src], &Ksh[b][0][ubase * 8]);
      gload_lds16(&Km[src], &Ksh[b][1][ubase * 8]);
      gload_lds16(&UTb[row * NCTX + j0 + c8 * 8], &Ush[b][ubase * 8]);
    }
  };

  f16x8 fqh[2], fqm[2];
  #pragma unroll
  for (int ks = 0; ks < 2; ++ks) {
    int off = (q0 + q16)*DH + 32*ks + colb;
    fqh[ks] = *(const f16x8*)&Qh[off];
    fqm[ks] = *(const f16x8*)&Qm[off];
  }

  float mrun = -3.0e38f, lrun = 0.f;
  f32x4 yacc[4] = {{0,0,0,0},{0,0,0,0},{0,0,0,0},{0,0,0,0}};

  if (t0 < t1) stage(0, t0);
  __syncthreads();

  int cur = 0;
  for (int t = t0; t < t1; ++t) {
    if (t + 1 < t1) stage(cur ^ 1, t + 1);
    if (t < Town) {
      const int j0 = t * 64;
      f32x4 sa[4] = {{0,0,0,0},{0,0,0,0},{0,0,0,0},{0,0,0,0}};
      #pragma unroll
      for (int ks = 0; ks < 2; ++ks) {
        #pragma unroll
        for (int st = 0; st < 4; ++st) {
          int row = 16*st + q16;
          int off = row * 64 + (((4*ks + grp) ^ (row & 7)) << 3);
          f16x8 kh = *(const f16x8*)&Ksh[cur][0][off];
          f16x8 km = *(const f16x8*)&Ksh[cur][1][off];
          sa[st] = __builtin_amdgcn_mfma_f32_16x16x32_f16(kh, fqh[ks], sa[st], 0,0,0);
          sa[st] = __builtin_amdgcn_mfma_f32_16x16x32_f16(kh, fqm[ks], sa[st], 0,0,0);
          sa[st] = __builtin_amdgcn_mfma_f32_16x16x32_f16(km, fqh[ks], sa[st], 0,0,0);
        }
      }
      #pragma unroll
      for (int st = 0; st < 4; ++st)
        #pragma unroll
        for (int r = 0; r < 4; ++r) {
          int key = j0 + 16*st + 4*grp + r;
          if (key > q) sa[st][r] = -3.0e38f;
        }
      float mx = sa[0][0];
      #pragma unroll
      for (int st = 0; st < 4; ++st)
        #pragma unroll
        for (int r = 0; r < 4; ++r) mx = fmaxf(mx, sa[st][r]);
      mx = fmaxf(mx, __shfl_xor(mx, 16));
      mx = fmaxf(mx, __shfl_xor(mx, 32));
      float mnew  = fmaxf(mrun, mx);
      float alpha = __expf(mrun - mnew);
      float ts = 0.f;
      ushort pb[16];
      #pragma unroll
      for (int st = 0; st < 4; ++st)
        #pragma unroll
        for (int r = 0; r < 4; ++r) {
          float p = __expf(sa[st][r] - mnew);
          ts += p;
          pb[st*4 + r] = f2h(p);
        }
      ts += __shfl_xor(ts, 16);
      ts += __shfl_xor(ts, 32);
      lrun = lrun * alpha + ts;
      mrun = mnew;
      float ar[4];
      #pragma unroll
      for (int r = 0; r < 4; ++r) ar[r] = __shfl(alpha, 4*grp + r, 64);
      #pragma unroll
      for (int dt = 0; dt < 4; ++dt) {
        yacc[dt][0] *= ar[0]; yacc[dt][1] *= ar[1];
        yacc[dt][2] *= ar[2]; yacc[dt][3] *= ar[3];
      }
      #pragma unroll
      for (int st = 0; st < 4; ++st) {
        uint2 v;
        v.x = (uint)pb[st*4+0] | ((uint)pb[st*4+1] << 16);
        v.y = (uint)pb[st*4+2] | ((uint)pb[st*4+3] << 16);
        *(uint2*)&psw[q16*72 + 16*st + 4*grp] = v;
      }
      __threadfence_block();
      __builtin_amdgcn_sched_barrier(0);
      #pragma unroll
      for (int ks = 0; ks < 2; ++ks) {
        f16x8 pa = *(const f16x8*)&psw[q16*72 + 32*ks + colb];
        #pragma unroll
        for (int dt = 0; dt < 4; ++dt) {
          int row = 16*dt + q16;
          int off = row * 64 + (((4*ks + grp) ^ (row & 7)) << 3);
          f16x8 ub = *(const f16x8*)&Ush[cur][off];
          yacc[dt] = __builtin_amdgcn_mfma_f32_16x16x32_f16(pa, ub, yacc[dt], 0,0,0);
        }
      }
    }
    __syncthreads();
    cur ^= 1;
  }
  if (grp == 0) {
    Pm[c * NCTX + q] = mrun;
    Pl[c * NCTX + q] = lrun;
  }
  #pragma unroll
  for (int dt = 0; dt < 4; ++dt)
    #pragma unroll
    for (int r = 0; r < 4; ++r)
      Py[(c * NCTX + q0 + 4*grp + r) * DH + 16*dt + q16] = yacc[dt][r];
}

// ---------------- PRIMARY: fused combine + out = Y @ W_vT via fp16 MFMA ---------
__global__ __launch_bounds__(256, 3) void out_fused_kernel(
    const float* __restrict__ Pm, const float* __restrict__ Pl,
    const float* __restrict__ Py,
    const ushort* __restrict__ WvTh, const ushort* __restrict__ WvTm,
    float* __restrict__ out)
{
  __shared__ __align__(16) ushort Yh[64*64], Ym[64*64];
  __shared__ __align__(16) ushort Wsh[128*64], Wsm[128*64];
  __shared__ float sden[NCH][64];
  __shared__ float invd[64];

  const int tid  = threadIdx.x;
  const int lane = tid & 63;
  const int w    = tid >> 6;
  const int q16  = lane & 15;
  const int grp  = lane >> 4;
  const int r0   = blockIdx.x * 64;
  const int cb   = blockIdx.y;

  #pragma unroll
  for (int u = 0; u < 4; ++u) {
    int ubase = u * 256 + w * 64;
    int unit  = ubase + lane;
    int row   = unit >> 3, slotp = unit & 7;
    int c8    = slotp ^ (row & 7);
    int src   = (cb * 128 + row) * 64 + c8 * 8;
    gload_lds16(&WvTh[src], &Wsh[ubase * 8]);
    gload_lds16(&WvTm[src], &Wsm[ubase * 8]);
  }
  if (tid < 64) {
    int rrow = r0 + tid;
    float mv[NCH]; float M = -3.0e38f;
    #pragma unroll
    for (int c = 0; c < NCH; ++c) {
      mv[c] = Pm[c*NCTX + rrow];
      M = fmaxf(M, mv[c]);
    }
    float den = 0.f;
    #pragma unroll
    for (int c = 0; c < NCH; ++c) {
      float s = __expf(mv[c] - M);
      sden[c][tid] = s;
      den += s * Pl[c*NCTX + rrow];
    }
    invd[tid] = 1.0f / den;
  }
  __syncthreads();

  #pragma unroll
  for (int it = 0; it < 4; ++it) {
    int idx = it * 256 + tid;
    int h4 = idx & 15, rr = idx >> 4;
    int rrow = r0 + rr;
    float nx = 0.f, ny = 0.f, nz = 0.f, nw = 0.f;
    #pragma unroll
    for (int c = 0; c < NCH; ++c) {
      float s = sden[c][rr];
      float4 p4 = *(const float4*)&Py[(c*NCTX + rrow)*DH + h4*4];
      nx += s*p4.x; ny += s*p4.y; nz += s*p4.z; nw += s*p4.w;
    }
    float inv = invd[rr];
    float yv[4] = {nx*inv, ny*inv, nz*inv, nw*inv};
    ushort hv[4], mv4[4];
    #pragma unroll
    for (int e = 0; e < 4; ++e) {
      ushort h = f2h(yv[e]);
      hv[e] = h;
      mv4[e] = f2h(yv[e] - h2f(h));
    }
    int off = rr*64 + (((h4 >> 1) ^ (rr & 7)) << 3) + (h4 & 1) * 4;
    uint2 vh, vm;
    vh.x = (uint)hv[0] | ((uint)hv[1] << 16);
    vh.y = (uint)hv[2] | ((uint)hv[3] << 16);
    vm.x = (uint)mv4[0] | ((uint)mv4[1] << 16);
    vm.y = (uint)mv4[2] | ((uint)mv4[3] << 16);
    *(uint2*)&Yh[off] = vh;
    *(uint2*)&Ym[off] = vm;
  }
  __syncthreads();

  f32x4 acc[4][2] = {};
  #pragma unroll
  for (int ks = 0; ks < 2; ++ks) {
    f16x8 ah[4], am[4];
    #pragma unroll
    for (int rt = 0; rt < 4; ++rt) {
      int row = 16*rt + q16;
      int off = row*64 + (((4*ks + grp) ^ (row & 7)) << 3);
      ah[rt] = *(const f16x8*)&Yh[off];
      am[rt] = *(const f16x8*)&Ym[off];
    }
    #pragma unroll
    for (int lt = 0; lt < 2; ++lt) {
      int crow = w*32 + lt*16 + q16;
      int off  = crow*64 + (((4*ks + grp) ^ (crow & 7)) << 3);
      f16x8 bh = *(const f16x8*)&Wsh[off];
      f16x8 bm = *(const f16x8*)&Wsm[off];
      #pragma unroll
      for (int rt = 0; rt < 4; ++rt) {
        acc[rt][lt] = __builtin_amdgcn_mfma_f32_16x16x32_f16(ah[rt], bh, acc[rt][lt], 0,0,0);
        acc[rt][lt] = __builtin_amdgcn_mfma_f32_16x16x32_f16(ah[rt], bm, acc[rt][lt], 0,0,0);
        acc[rt][lt] = __builtin_amdgcn_mfma_f32_16x16x32_f16(am[rt], bh, acc[rt][lt], 0,0,0);
      }
    }
  }
  #pragma unroll
  for (int rt = 0; rt < 4; ++rt)
    #pragma unroll
    for (int lt = 0; lt < 2; ++lt)
      #pragma unroll
      for (int r = 0; r < 4; ++r)
        out[(r0 + 16*rt + 4*grp + r) * DM + cb*128 + w*32 + lt*16 + q16] = acc[rt][lt][r];
}

// ---------------- FALLBACK path: combine -> ws digit arrays --------------------
__global__ __launch_bounds__(256) void combine_kernel(
    const float* __restrict__ Pm, const float* __restrict__ Pl,
    const float* __restrict__ Py,
    ushort* __restrict__ Yh, ushort* __restrict__ Ym)
{
  int idx = blockIdx.x * 256 + threadIdx.x;
  int r = idx >> 6, d = idx & 63;
  float mv[NCH];
  float M = -3.0e38f;
  #pragma unroll
  for (int c = 0; c < NCH; ++c) {
    mv[c] = Pm[c*NCTX + r];
    M = fmaxf(M, mv[c]);
  }
  float num = 0.f, den = 0.f;
  #pragma unroll
  for (int c = 0; c < NCH; ++c) {
    float s = __expf(mv[c] - M);
    den += s * Pl[c*NCTX + r];
    num += s * Py[(c*NCTX + r)*DH + d];
  }
  float y = num / den;
  ushort h = f2h(y);
  Yh[idx] = h;
  Ym[idx] = f2h(y - h2f(h));
}

// ---------------- FALLBACK: out = Y @ W_vT via fp16 MFMA (reads ws only) -------
__global__ __launch_bounds__(256, 3) void out_mfma_kernel(
    const ushort* __restrict__ Yh_g, const ushort* __restrict__ Ym_g,
    const ushort* __restrict__ WvTh, const ushort* __restrict__ WvTm,
    float* __restrict__ out)
{
  __shared__ __align__(16) ushort Yh[64*64], Ym[64*64];
  __shared__ __align__(16) ushort Wsh[128*64], Wsm[128*64];

  const int tid  = threadIdx.x;
  const int lane = tid & 63;
  const int w    = tid >> 6;
  const int q16  = lane & 15;
  const int grp  = lane >> 4;
  const int r0   = blockIdx.x * 64;
  const int cb   = blockIdx.y;

  #pragma unroll
  for (int it = 0; it < 2; ++it) {
    int ubase = it * 256 + w * 64;
    int unit  = ubase + lane;
    int row   = unit >> 3, slotp = unit & 7;
    int c8    = slotp ^ (row & 7);
    int src   = (r0 + row) * 64 + c8 * 8;
    gload_lds16(&Yh_g[src], &Yh[ubase * 8]);
    gload_lds16(&Ym_g[src], &Ym[ubase * 8]);
  }
  #pragma unroll
  for (int u = 0; u < 4; ++u) {
    int ubase = u * 256 + w * 64;
    int unit  = ubase + lane;
    int row   = unit >> 3, slotp = unit & 7;
    int c8    = slotp ^ (row & 7);
    int src   = (cb * 128 + row) * 64 + c8 * 8;
    gload_lds16(&WvTh[src], &Wsh[ubase * 8]);
    gload_lds16(&WvTm[src], &Wsm[ubase * 8]);
  }
  __syncthreads();

  f32x4 acc[4][2] = {};
  #pragma unroll
  for (int ks = 0; ks < 2; ++ks) {
    f16x8 ah[4], am[4];
    #pragma unroll
    for (int rt = 0; rt < 4; ++rt) {
      int row = 16*rt + q16;
      int off = row*64 + (((4*ks + grp) ^ (row & 7)) << 3);
      ah[rt] = *(const f16x8*)&Yh[off];
      am[rt] = *(const f16x8*)&Ym[off];
    }
    #pragma unroll
    for (int lt = 0; lt < 2; ++lt) {
      int crow = w*32 + lt*16 + q16;
      int off  = crow*64 + (((4*ks + grp) ^ (crow & 7)) << 3);
      f16x8 bh = *(const f16x8*)&Wsh[off];
      f16x8 bm = *(const f16x8*)&Wsm[off];
      #pragma unroll
      for (int rt = 0; rt < 4; ++rt) {
        acc[rt][lt] = __builtin_amdgcn_mfma_f32_16x16x32_f16(ah[rt], bh, acc[rt][lt], 0,0,0);
        acc[rt][lt] = __builtin_amdgcn_mfma_f32_16x16x32_f16(ah[rt], bm, acc[rt][lt], 0,0,0);
        acc[rt][lt] = __builtin_amdgcn_mfma_f32_16x16x32_f16(am[rt], bh, acc[rt][lt], 0,0,0);
      }
    }
  }
  #pragma unroll
  for (int rt = 0; rt < 4; ++rt)
    #pragma unroll
    for (int lt = 0; lt < 2; ++lt)
      #pragma unroll
      for (int r = 0; r < 4; ++r)
        out[(r0 + 16*rt + 4*grp + r) * DM + cb*128 + w*32 + lt*16 + q16] = acc[rt][lt][r];
}

extern "C" void kernel_launch(void* const* d_in, const int* in_sizes, int n_in,
                              void* d_out, int out_size, void* d_ws, size_t ws_size,
                              hipStream_t stream) {
  const float* x   = (const float*)d_in[0];
  const float* Wq  = (const float*)d_in[1];
  const float* WkT = (const float*)d_in[2];
  const float* Wo  = (const float*)d_in[3];
  const float* Wv  = (const float*)d_in[4];
  float* out = (float*)d_out;
  char*  ob  = (char*)d_out;   // scratch until the final kernel overwrites it
  char*  wb  = (char*)d_ws;    // race-free scratch for the final kernel

  ushort* Qhp = (ushort*)(ob + D_QH);
  ushort* Qmp = (ushort*)(ob + D_QM);
  ushort* Khp = (ushort*)(ob + D_KH);
  ushort* Kmp = (ushort*)(ob + D_KM);
  ushort* UTb = (ushort*)(ob + D_UTB);
  ushort* WTh = (ushort*)(ob + D_WTH);
  ushort* WTm = (ushort*)(ob + D_WTM);

  ushort* WvTh = (ushort*)(wb + S_WVH);
  ushort* WvTm = (ushort*)(wb + S_WVM);

  const bool big_ws = (ws_size >= (size_t)S_END);   // constant per process

  float* Pmp = big_ws ? (float*)(wb + S_PM) : (float*)(ob + D_PM);
  float* Plp = big_ws ? (float*)(wb + S_PL) : (float*)(ob + D_PL);
  float* Pyp = big_ws ? (float*)(wb + S_PY) : (float*)(ob + D_PY);

  hipLaunchKernelGGL(wsplit_kernel, dim3(1024), dim3(256), 0, stream,
                     Wq, WkT, Wo, Wv, WTh, WTm, WvTh, WvTm);
  hipLaunchKernelGGL(proj_mfma_kernel, dim3(256, 3), dim3(256), 0, stream,
                     x, WTh, WTm, Qhp, Qmp, Khp, Kmp, UTb);
  hipLaunchKernelGGL(attn_kernel, dim3(512), dim3(256), 0, stream,
                     Qhp, Qmp, Khp, Kmp, UTb, Pmp, Plp, Pyp);
  if (big_ws) {
    hipLaunchKernelGGL(out_fused_kernel, dim3(64, 8), dim3(256), 0, stream,
                       Pmp, Plp, Pyp, WvTh, WvTm, out);
  } else {
    ushort* Yhp = (ushort*)(wb + S_YH);
    ushort* Ymp = (ushort*)(wb + S_YM);
    hipLaunchKernelGGL(combine_kernel, dim3(1024), dim3(256), 0, stream,
                       Pmp, Plp, Pyp, Yhp, Ymp);
    hipLaunchKernelGGL(out_mfma_kernel, dim3(64, 8), dim3(256), 0, stream,
                       Yhp, Ymp, WvTh, WvTm, out);
  }
}

// Round 27
// 52.873 us; speedup vs baseline: 1.0961x; 1.0961x over previous
//
#include <hip/hip_runtime.h>
#include <hip/hip_bf16.h>
#include <math.h>

#define DM    1024
#define DH    64
#define NCTX  4096
#define NCH   8        // key-chunks per q-group

typedef __attribute__((ext_vector_type(8))) _Float16 f16x8;
typedef __attribute__((ext_vector_type(4))) float f32x4;

// ---- d_out scratch (16 MiB): written by wsplit/proj, consumed by proj/attn;
// the final kernel reads ONLY d_ws and overwrites d_out (race-free).
#define D_QH   0
#define D_QM   524288
#define D_KH   1572864
#define D_KM   2097152
#define D_UTB  3145728
#define D_PY   3670016    // fallback-path partials live here
#define D_PM   12058624
#define D_PL   12189696
#define D_WTH  12320768
#define D_WTM  12713984   // end 13107200

// ---- d_ws layout. WvT digits always at 0. Primary path (ws >= 8.5 MiB):
// partials in ws -> fused combine+out reads only ws.
#define S_WVH  0          // 128 KiB fp16 WvT^t high [1024][64]
#define S_WVM  131072     // 128 KiB
#define S_PM   262144     // 128 KiB f32 [NCH][NCTX]
#define S_PL   393216     // 128 KiB
#define S_PY   524288     // 8 MiB f32 [NCH][NCTX][DH]
#define S_END  8912896
// Fallback path: Y digit arrays in ws
#define S_YH   262144     // 512 KiB
#define S_YM   786432     // 512 KiB (end 1310720 < 4456448 proven)

__device__ __forceinline__ ushort f2h(float x) {
  _Float16 h = (_Float16)x;
  return __builtin_bit_cast(ushort, h);
}
__device__ __forceinline__ float h2f(ushort u) {
  return (float)__builtin_bit_cast(_Float16, u);
}

// async global->LDS, 16B/lane: LDS dest wave-uniform base + lane*16;
// global src per-lane (pre-swizzled source, linear LDS dest -- rule #21).
typedef __attribute__((address_space(1))) const unsigned int gas_u32;
typedef __attribute__((address_space(3))) unsigned int las_u32;
__device__ __forceinline__ void gload_lds16(const void* g, void* l) {
  __builtin_amdgcn_global_load_lds((gas_u32*)g, (las_u32*)l, 16, 0, 0);
}

// ---------------- W -> WT fp16 2-digit split (r22-validated) ----------
__global__ __launch_bounds__(256) void wsplit_kernel(
    const float* __restrict__ Wq, const float* __restrict__ WkT,
    const float* __restrict__ Wo, const float* __restrict__ Wv,
    ushort* __restrict__ WTh, ushort* __restrict__ WTm,
    ushort* __restrict__ WvTh, ushort* __restrict__ WvTm)
{
  int gid = blockIdx.x * 256 + threadIdx.x;
  int mat = gid >> 16;
  int idx = gid & 65535;
  if (mat == 3) {
    float v = Wv[idx];                 // Wv[h][c], coalesced read
    int h = idx >> 10, c = idx & 1023;
    int oidx = c * 64 + h;             // WvT^t[c][h]
    ushort h16 = f2h(v);
    WvTh[oidx] = h16;
    WvTm[oidx] = f2h(v - h2f(h16));
    return;
  }
  float v; int oidx;
  if (mat == 1) {
    v = WkT[idx];
    oidx = 65536 + idx;
  } else {
    int k = idx >> 6, h = idx & 63;
    v = (mat == 0 ? Wq : Wo)[idx];
    oidx = mat * 65536 + h * 1024 + k;
  }
  ushort h16 = f2h(v);
  float rem = v - h2f(h16);
  WTh[oidx] = h16;
  WTm[oidx] = f2h(rem);
}

// ---------------- projections via MFMA: fp16 2-digit, 3 products ----------------
// r25-validated 32-row/(128,3) version (r26's 16-row rebalance regressed:
// it doubled W-staging amortization cost; reverted).
__global__ __launch_bounds__(256, 2) void proj_mfma_kernel(
    const float* __restrict__ x,
    const ushort* __restrict__ WTh, const ushort* __restrict__ WTm,
    ushort* __restrict__ Qh, ushort* __restrict__ Qm,
    ushort* __restrict__ Kh, ushort* __restrict__ Km,
    ushort* __restrict__ UTb)
{
  __shared__ __align__(16) ushort xsh[32*128], xsm[32*128];
  __shared__ __align__(16) ushort wsh[2][64*128], wsm[2][64*128];

  const int tid  = threadIdx.x;
  const int lane = tid & 63;
  const int w    = tid >> 6;
  const int q16  = lane & 15;
  const int grp  = lane >> 4;
  const int r0   = blockIdx.x * 32;
  const int mat  = blockIdx.y;
  const ushort* __restrict__ wh = WTh + mat * 65536;
  const ushort* __restrict__ wm = WTm + mat * 65536;

  const int rw  = (w & 1) * 16;
  const int ct0 = (w >> 1) * 2;

  const int xrowl = tid >> 4, xslot = tid & 15;

  auto stage_w = [&](int b, int s) {
    const int kp0 = s * 128;
    #pragma unroll
    for (int u = 0; u < 4; ++u) {
      int ubase = u * 256 + w * 64;
      int unit  = ubase + lane;
      int row   = unit >> 4, slotp = unit & 15;
      int ssrc  = slotp ^ (row & 15);
      int gsrc  = row * DM + kp0 + ssrc * 8;
      gload_lds16(&wh[gsrc], &wsh[b][ubase * 8]);
      gload_lds16(&wm[gsrc], &wsm[b][ubase * 8]);
    }
  };
  auto xload = [&](int s, float4& a0, float4& a1, float4& b0, float4& b1) {
    const int kp0 = s * 128;
    const float* s0 = &x[(r0 + xrowl) * DM + kp0 + xslot * 8];
    const float* s1 = &x[(r0 + xrowl + 16) * DM + kp0 + xslot * 8];
    a0 = *(const float4*)&s0[0]; a1 = *(const float4*)&s0[4];
    b0 = *(const float4*)&s1[0]; b1 = *(const float4*)&s1[4];
  };
  auto xsplit_write = [&](float4 a0, float4 a1, float4 b0, float4 b1) {
    float xv0[8] = {a0.x,a0.y,a0.z,a0.w,a1.x,a1.y,a1.z,a1.w};
    float xv1[8] = {b0.x,b0.y,b0.z,b0.w,b1.x,b1.y,b1.z,b1.w};
    ushort hv0[8], mv0[8], hv1[8], mv1[8];
    #pragma unroll
    for (int e = 0; e < 8; ++e) {
      ushort h0 = f2h(xv0[e]);
      hv0[e] = h0;  mv0[e] = f2h(xv0[e] - h2f(h0));
      ushort h1 = f2h(xv1[e]);
      hv1[e] = h1;  mv1[e] = f2h(xv1[e] - h2f(h1));
    }
    int d0 = xrowl * 128 + ((xslot ^ (xrowl & 15)) << 3);
    int r1 = xrowl + 16;
    int d1 = r1 * 128 + ((xslot ^ (r1 & 15)) << 3);
    #pragma unroll
    for (int e = 0; e < 8; ++e) {
      xsh[d0+e] = hv0[e]; xsm[d0+e] = mv0[e];
      xsh[d1+e] = hv1[e]; xsm[d1+e] = mv1[e];
    }
  };

  f32x4 acc[2] = {{0,0,0,0},{0,0,0,0}};

  {
    float4 a0, a1, b0, b1;
    xload(0, a0, a1, b0, b1);
    xsplit_write(a0, a1, b0, b1);
    stage_w(0, 0);
  }
  __syncthreads();

  int cur = 0;
  for (int stg = 0; stg < 8; ++stg) {
    float4 na0, na1, nb0, nb1;
    if (stg < 7) {
      xload(stg + 1, na0, na1, nb0, nb1);
      stage_w(cur ^ 1, stg + 1);
    }
    #pragma unroll
    for (int ksub = 0; ksub < 4; ++ksub) {
      const int s = ksub * 4 + grp;
      const int xrow = rw + q16;
      f16x8 xh8 = *(const f16x8*)&xsh[xrow * 128 + ((s ^ (xrow & 15)) << 3)];
      f16x8 xm8 = *(const f16x8*)&xsm[xrow * 128 + ((s ^ (xrow & 15)) << 3)];
      #pragma unroll
      for (int i = 0; i < 2; ++i) {
        const int wrow = (ct0 + i) * 16 + q16;
        const int woff = wrow * 128 + ((s ^ (wrow & 15)) << 3);
        f16x8 bh = *(const f16x8*)&wsh[cur][woff];
        f16x8 bm = *(const f16x8*)&wsm[cur][woff];
        if (mat == 2) {   // A = W, B = x (validated operand pattern)
          acc[i] = __builtin_amdgcn_mfma_f32_16x16x32_f16(bh, xh8, acc[i], 0,0,0);
          acc[i] = __builtin_amdgcn_mfma_f32_16x16x32_f16(bh, xm8, acc[i], 0,0,0);
          acc[i] = __builtin_amdgcn_mfma_f32_16x16x32_f16(bm, xh8, acc[i], 0,0,0);
        } else {          // A = x, B = W
          acc[i] = __builtin_amdgcn_mfma_f32_16x16x32_f16(xh8, bh, acc[i], 0,0,0);
          acc[i] = __builtin_amdgcn_mfma_f32_16x16x32_f16(xh8, bm, acc[i], 0,0,0);
          acc[i] = __builtin_amdgcn_mfma_f32_16x16x32_f16(xm8, bh, acc[i], 0,0,0);
        }
      }
    }
    __syncthreads();
    if (stg < 7) xsplit_write(na0, na1, nb0, nb1);
    __syncthreads();
    cur ^= 1;
  }

  if (mat == 2) {
    #pragma unroll
    for (int i = 0; i < 2; ++i)
      #pragma unroll
      for (int r = 0; r < 4; ++r)
        UTb[((ct0 + i)*16 + 4*grp + r) * NCTX + r0 + rw + q16] = f2h(acc[i][r]);
  } else {
    ushort* __restrict__ Dh = (mat == 0) ? Qh : Kh;
    ushort* __restrict__ Dm = (mat == 0) ? Qm : Km;
    #pragma unroll
    for (int i = 0; i < 2; ++i)
      #pragma unroll
      for (int r = 0; r < 4; ++r) {
        float v = acc[i][r];
        ushort h = f2h(v);
        ushort m = f2h(v - h2f(h));
        int idx = (r0 + rw + 4*grp + r) * DH + (ct0 + i)*16 + q16;
        Dh[idx] = h; Dm[idx] = m;
      }
  }
}

// ---------------- MFMA flash attention: fp16 2-digit scores (r25-validated) -----
__global__ __launch_bounds__(256, 2) void attn_kernel(
    const ushort* __restrict__ Qh, const ushort* __restrict__ Qm,
    const ushort* __restrict__ Kh, const ushort* __restrict__ Km,
    const ushort* __restrict__ UTb,
    float* __restrict__ Pm, float* __restrict__ Pl, float* __restrict__ Py)
{
  __shared__ ushort Ksh[2][2][64*64];              // 32 KiB
  __shared__ ushort Ush[2][64*64];                 // 16 KiB
  __shared__ __align__(16) ushort ps[4][16*72];    //  9 KiB

  const int tid  = threadIdx.x;
  const int lane = tid & 63;
  const int w    = tid >> 6;
  ushort* psw = ps[w];
  const int q16  = lane & 15;
  const int grp  = lane >> 4;
  const int colb = grp * 8;

  const int bid = blockIdx.x;           // 0..511
  const int j   = bid & 255;
  const int hi  = bid >> 8;
  const int qq  = hi ? (63 - (j & 63)) : (j & 63);
  const int c   = (j >> 6) + hi * 4;    // bijective onto (qq, c) pairs

  const int gbase = 252 - 4 * qq;
  const int g     = gbase + w;
  const int gmax  = gbase + 3;
  const int T     = ((16*gmax + 15) >> 6) + 1;
  const int t0 = (c * T) >> 3, t1 = ((c+1) * T) >> 3;
  const int Town = ((16*g + 15) >> 6) + 1;
  const int q0 = 16 * g;
  const int q  = q0 + q16;

  auto stage = [&](int b, int t) {
    const int j0 = t * 64;
    #pragma unroll
    for (int it = 0; it < 2; ++it) {
      int ubase = it * 256 + w * 64;
      int unit  = ubase + lane;
      int row   = unit >> 3, slotp = unit & 7;
      int c8    = slotp ^ (row & 7);
      int src   = (j0 + row) * DH + c8 * 8;
      gload_lds16(&Kh[src], &Ksh[b][0][ubase * 8]);
      gload_lds16(&Km[src], &Ksh[b][1][ubase * 8]);
      gload_lds16(&UTb[row * NCTX + j0 + c8 * 8], &Ush[b][ubase * 8]);
    }
  };

  f16x8 fqh[2], fqm[2];
  #pragma unroll
  for (int ks = 0; ks < 2; ++ks) {
    int off = (q0 + q16)*DH + 32*ks + colb;
    fqh[ks] = *(const f16x8*)&Qh[off];
    fqm[ks] = *(const f16x8*)&Qm[off];
  }

  float mrun = -3.0e38f, lrun = 0.f;
  f32x4 yacc[4] = {{0,0,0,0},{0,0,0,0},{0,0,0,0},{0,0,0,0}};

  if (t0 < t1) stage(0, t0);
  __syncthreads();

  int cur = 0;
  for (int t = t0; t < t1; ++t) {
    if (t + 1 < t1) stage(cur ^ 1, t + 1);
    if (t < Town) {
      const int j0 = t * 64;
      f32x4 sa[4] = {{0,0,0,0},{0,0,0,0},{0,0,0,0},{0,0,0,0}};
      #pragma unroll
      for (int ks = 0; ks < 2; ++ks) {
        #pragma unroll
        for (int st = 0; st < 4; ++st) {
          int row = 16*st + q16;
          int off = row * 64 + (((4*ks + grp) ^ (row & 7)) << 3);
          f16x8 kh = *(const f16x8*)&Ksh[cur][0][off];
          f16x8 km = *(const f16x8*)&Ksh[cur][1][off];
          sa[st] = __builtin_amdgcn_mfma_f32_16x16x32_f16(kh, fqh[ks], sa[st], 0,0,0);
          sa[st] = __builtin_amdgcn_mfma_f32_16x16x32_f16(kh, fqm[ks], sa[st], 0,0,0);
          sa[st] = __builtin_amdgcn_mfma_f32_16x16x32_f16(km, fqh[ks], sa[st], 0,0,0);
        }
      }
      #pragma unroll
      for (int st = 0; st < 4; ++st)
        #pragma unroll
        for (int r = 0; r < 4; ++r) {
          int key = j0 + 16*st + 4*grp + r;
          if (key > q) sa[st][r] = -3.0e38f;
        }
      float mx = sa[0][0];
      #pragma unroll
      for (int st = 0; st < 4; ++st)
        #pragma unroll
        for (int r = 0; r < 4; ++r) mx = fmaxf(mx, sa[st][r]);
      mx = fmaxf(mx, __shfl_xor(mx, 16));
      mx = fmaxf(mx, __shfl_xor(mx, 32));
      float mnew  = fmaxf(mrun, mx);
      float alpha = __expf(mrun - mnew);
      float ts = 0.f;
      ushort pb[16];
      #pragma unroll
      for (int st = 0; st < 4; ++st)
        #pragma unroll
        for (int r = 0; r < 4; ++r) {
          float p = __expf(sa[st][r] - mnew);
          ts += p;
          pb[st*4 + r] = f2h(p);
        }
      ts += __shfl_xor(ts, 16);
      ts += __shfl_xor(ts, 32);
      lrun = lrun * alpha + ts;
      mrun = mnew;
      float ar[4];
      #pragma unroll
      for (int r = 0; r < 4; ++r) ar[r] = __shfl(alpha, 4*grp + r, 64);
      #pragma unroll
      for (int dt = 0; dt < 4; ++dt) {
        yacc[dt][0] *= ar[0]; yacc[dt][1] *= ar[1];
        yacc[dt][2] *= ar[2]; yacc[dt][3] *= ar[3];
      }
      #pragma unroll
      for (int st = 0; st < 4; ++st) {
        uint2 v;
        v.x = (uint)pb[st*4+0] | ((uint)pb[st*4+1] << 16);
        v.y = (uint)pb[st*4+2] | ((uint)pb[st*4+3] << 16);
        *(uint2*)&psw[q16*72 + 16*st + 4*grp] = v;
      }
      __threadfence_block();
      __builtin_amdgcn_sched_barrier(0);
      #pragma unroll
      for (int ks = 0; ks < 2; ++ks) {
        f16x8 pa = *(const f16x8*)&psw[q16*72 + 32*ks + colb];
        #pragma unroll
        for (int dt = 0; dt < 4; ++dt) {
          int row = 16*dt + q16;
          int off = row * 64 + (((4*ks + grp) ^ (row & 7)) << 3);
          f16x8 ub = *(const f16x8*)&Ush[cur][off];
          yacc[dt] = __builtin_amdgcn_mfma_f32_16x16x32_f16(pa, ub, yacc[dt], 0,0,0);
        }
      }
    }
    __syncthreads();
    cur ^= 1;
  }
  if (grp == 0) {
    Pm[c * NCTX + q] = mrun;
    Pl[c * NCTX + q] = lrun;
  }
  #pragma unroll
  for (int dt = 0; dt < 4; ++dt)
    #pragma unroll
    for (int r = 0; r < 4; ++r)
      Py[(c * NCTX + q0 + 4*grp + r) * DH + 16*dt + q16] = yacc[dt][r];
}

// ---------------- PRIMARY: fused combine + out = Y @ W_vT via fp16 MFMA ---------
__global__ __launch_bounds__(256, 3) void out_fused_kernel(
    const float* __restrict__ Pm, const float* __restrict__ Pl,
    const float* __restrict__ Py,
    const ushort* __restrict__ WvTh, const ushort* __restrict__ WvTm,
    float* __restrict__ out)
{
  __shared__ __align__(16) ushort Yh[64*64], Ym[64*64];
  __shared__ __align__(16) ushort Wsh[128*64], Wsm[128*64];
  __shared__ float sden[NCH][64];
  __shared__ float invd[64];

  const int tid  = threadIdx.x;
  const int lane = tid & 63;
  const int w    = tid >> 6;
  const int q16  = lane & 15;
  const int grp  = lane >> 4;
  const int r0   = blockIdx.x * 64;
  const int cb   = blockIdx.y;

  #pragma unroll
  for (int u = 0; u < 4; ++u) {
    int ubase = u * 256 + w * 64;
    int unit  = ubase + lane;
    int row   = unit >> 3, slotp = unit & 7;
    int c8    = slotp ^ (row & 7);
    int src   = (cb * 128 + row) * 64 + c8 * 8;
    gload_lds16(&WvTh[src], &Wsh[ubase * 8]);
    gload_lds16(&WvTm[src], &Wsm[ubase * 8]);
  }
  if (tid < 64) {
    int rrow = r0 + tid;
    float mv[NCH]; float M = -3.0e38f;
    #pragma unroll
    for (int c = 0; c < NCH; ++c) {
      mv[c] = Pm[c*NCTX + rrow];
      M = fmaxf(M, mv[c]);
    }
    float den = 0.f;
    #pragma unroll
    for (int c = 0; c < NCH; ++c) {
      float s = __expf(mv[c] - M);
      sden[c][tid] = s;
      den += s * Pl[c*NCTX + rrow];
    }
    invd[tid] = 1.0f / den;
  }
  __syncthreads();

  #pragma unroll
  for (int it = 0; it < 4; ++it) {
    int idx = it * 256 + tid;
    int h4 = idx & 15, rr = idx >> 4;
    int rrow = r0 + rr;
    float nx = 0.f, ny = 0.f, nz = 0.f, nw = 0.f;
    #pragma unroll
    for (int c = 0; c < NCH; ++c) {
      float s = sden[c][rr];
      float4 p4 = *(const float4*)&Py[(c*NCTX + rrow)*DH + h4*4];
      nx += s*p4.x; ny += s*p4.y; nz += s*p4.z; nw += s*p4.w;
    }
    float inv = invd[rr];
    float yv[4] = {nx*inv, ny*inv, nz*inv, nw*inv};
    ushort hv[4], mv4[4];
    #pragma unroll
    for (int e = 0; e < 4; ++e) {
      ushort h = f2h(yv[e]);
      hv[e] = h;
      mv4[e] = f2h(yv[e] - h2f(h));
    }
    int off = rr*64 + (((h4 >> 1) ^ (rr & 7)) << 3) + (h4 & 1) * 4;
    uint2 vh, vm;
    vh.x = (uint)hv[0] | ((uint)hv[1] << 16);
    vh.y = (uint)hv[2] | ((uint)hv[3] << 16);
    vm.x = (uint)mv4[0] | ((uint)mv4[1] << 16);
    vm.y = (uint)mv4[2] | ((uint)mv4[3] << 16);
    *(uint2*)&Yh[off] = vh;
    *(uint2*)&Ym[off] = vm;
  }
  __syncthreads();

  f32x4 acc[4][2] = {};
  #pragma unroll
  for (int ks = 0; ks < 2; ++ks) {
    f16x8 ah[4], am[4];
    #pragma unroll
    for (int rt = 0; rt < 4; ++rt) {
      int row = 16*rt + q16;
      int off = row*64 + (((4*ks + grp) ^ (row & 7)) << 3);
      ah[rt] = *(const f16x8*)&Yh[off];
      am[rt] = *(const f16x8*)&Ym[off];
    }
    #pragma unroll
    for (int lt = 0; lt < 2; ++lt) {
      int crow = w*32 + lt*16 + q16;
      int off  = crow*64 + (((4*ks + grp) ^ (crow & 7)) << 3);
      f16x8 bh = *(const f16x8*)&Wsh[off];
      f16x8 bm = *(const f16x8*)&Wsm[off];
      #pragma unroll
      for (int rt = 0; rt < 4; ++rt) {
        acc[rt][lt] = __builtin_amdgcn_mfma_f32_16x16x32_f16(ah[rt], bh, acc[rt][lt], 0,0,0);
        acc[rt][lt] = __builtin_amdgcn_mfma_f32_16x16x32_f16(ah[rt], bm, acc[rt][lt], 0,0,0);
        acc[rt][lt] = __builtin_amdgcn_mfma_f32_16x16x32_f16(am[rt], bh, acc[rt][lt], 0,0,0);
      }
    }
  }
  #pragma unroll
  for (int rt = 0; rt < 4; ++rt)
    #pragma unroll
    for (int lt = 0; lt < 2; ++lt)
      #pragma unroll
      for (int r = 0; r < 4; ++r)
        out[(r0 + 16*rt + 4*grp + r) * DM + cb*128 + w*32 + lt*16 + q16] = acc[rt][lt][r];
}

// ---------------- FALLBACK path: combine -> ws digit arrays --------------------
__global__ __launch_bounds__(256) void combine_kernel(
    const float* __restrict__ Pm, const float* __restrict__ Pl,
    const float* __restrict__ Py,
    ushort* __restrict__ Yh, ushort* __restrict__ Ym)
{
  int idx = blockIdx.x * 256 + threadIdx.x;
  int r = idx >> 6, d = idx & 63;
  float mv[NCH];
  float M = -3.0e38f;
  #pragma unroll
  for (int c = 0; c < NCH; ++c) {
    mv[c] = Pm[c*NCTX + r];
    M = fmaxf(M, mv[c]);
  }
  float num = 0.f, den = 0.f;
  #pragma unroll
  for (int c = 0; c < NCH; ++c) {
    float s = __expf(mv[c] - M);
    den += s * Pl[c*NCTX + r];
    num += s * Py[(c*NCTX + r)*DH + d];
  }
  float y = num / den;
  ushort h = f2h(y);
  Yh[idx] = h;
  Ym[idx] = f2h(y - h2f(h));
}

// ---------------- FALLBACK: out = Y @ W_vT via fp16 MFMA (reads ws only) -------
__global__ __launch_bounds__(256, 3) void out_mfma_kernel(
    const ushort* __restrict__ Yh_g, const ushort* __restrict__ Ym_g,
    const ushort* __restrict__ WvTh, const ushort* __restrict__ WvTm,
    float* __restrict__ out)
{
  __shared__ __align__(16) ushort Yh[64*64], Ym[64*64];
  __shared__ __align__(16) ushort Wsh[128*64], Wsm[128*64];

  const int tid  = threadIdx.x;
  const int lane = tid & 63;
  const int w    = tid >> 6;
  const int q16  = lane & 15;
  const int grp  = lane >> 4;
  const int r0   = blockIdx.x * 64;
  const int cb   = blockIdx.y;

  #pragma unroll
  for (int it = 0; it < 2; ++it) {
    int ubase = it * 256 + w * 64;
    int unit  = ubase + lane;
    int row   = unit >> 3, slotp = unit & 7;
    int c8    = slotp ^ (row & 7);
    int src   = (r0 + row) * 64 + c8 * 8;
    gload_lds16(&Yh_g[src], &Yh[ubase * 8]);
    gload_lds16(&Ym_g[src], &Ym[ubase * 8]);
  }
  #pragma unroll
  for (int u = 0; u < 4; ++u) {
    int ubase = u * 256 + w * 64;
    int unit  = ubase + lane;
    int row   = unit >> 3, slotp = unit & 7;
    int c8    = slotp ^ (row & 7);
    int src   = (cb * 128 + row) * 64 + c8 * 8;
    gload_lds16(&WvTh[src], &Wsh[ubase * 8]);
    gload_lds16(&WvTm[src], &Wsm[ubase * 8]);
  }
  __syncthreads();

  f32x4 acc[4][2] = {};
  #pragma unroll
  for (int ks = 0; ks < 2; ++ks) {
    f16x8 ah[4], am[4];
    #pragma unroll
    for (int rt = 0; rt < 4; ++rt) {
      int row = 16*rt + q16;
      int off = row*64 + (((4*ks + grp) ^ (row & 7)) << 3);
      ah[rt] = *(const f16x8*)&Yh[off];
      am[rt] = *(const f16x8*)&Ym[off];
    }
    #pragma unroll
    for (int lt = 0; lt < 2; ++lt) {
      int crow = w*32 + lt*16 + q16;
      int off  = crow*64 + (((4*ks + grp) ^ (crow & 7)) << 3);
      f16x8 bh = *(const f16x8*)&Wsh[off];
      f16x8 bm = *(const f16x8*)&Wsm[off];
      #pragma unroll
      for (int rt = 0; rt < 4; ++rt) {
        acc[rt][lt] = __builtin_amdgcn_mfma_f32_16x16x32_f16(ah[rt], bh, acc[rt][lt], 0,0,0);
        acc[rt][lt] = __builtin_amdgcn_mfma_f32_16x16x32_f16(ah[rt], bm, acc[rt][lt], 0,0,0);
        acc[rt][lt] = __builtin_amdgcn_mfma_f32_16x16x32_f16(am[rt], bh, acc[rt][lt], 0,0,0);
      }
    }
  }
  #pragma unroll
  for (int rt = 0; rt < 4; ++rt)
    #pragma unroll
    for (int lt = 0; lt < 2; ++lt)
      #pragma unroll
      for (int r = 0; r < 4; ++r)
        out[(r0 + 16*rt + 4*grp + r) * DM + cb*128 + w*32 + lt*16 + q16] = acc[rt][lt][r];
}

extern "C" void kernel_launch(void* const* d_in, const int* in_sizes, int n_in,
                              void* d_out, int out_size, void* d_ws, size_t ws_size,
                              hipStream_t stream) {
  const float* x   = (const float*)d_in[0];
  const float* Wq  = (const float*)d_in[1];
  const float* WkT = (const float*)d_in[2];
  const float* Wo  = (const float*)d_in[3];
  const float* Wv  = (const float*)d_in[4];
  float* out = (float*)d_out;
  char*  ob  = (char*)d_out;   // scratch until the final kernel overwrites it
  char*  wb  = (char*)d_ws;    // race-free scratch for the final kernel

  ushort* Qhp = (ushort*)(ob + D_QH);
  ushort* Qmp = (ushort*)(ob + D_QM);
  ushort* Khp = (ushort*)(ob + D_KH);
  ushort* Kmp = (ushort*)(ob + D_KM);
  ushort* UTb = (ushort*)(ob + D_UTB);
  ushort* WTh = (ushort*)(ob + D_WTH);
  ushort* WTm = (ushort*)(ob + D_WTM);

  ushort* WvTh = (ushort*)(wb + S_WVH);
  ushort* WvTm = (ushort*)(wb + S_WVM);

  const bool big_ws = (ws_size >= (size_t)S_END);   // constant per process

  float* Pmp = big_ws ? (float*)(wb + S_PM) : (float*)(ob + D_PM);
  float* Plp = big_ws ? (float*)(wb + S_PL) : (float*)(ob + D_PL);
  float* Pyp = big_ws ? (float*)(wb + S_PY) : (float*)(ob + D_PY);

  hipLaunchKernelGGL(wsplit_kernel, dim3(1024), dim3(256), 0, stream,
                     Wq, WkT, Wo, Wv, WTh, WTm, WvTh, WvTm);
  hipLaunchKernelGGL(proj_mfma_kernel, dim3(128, 3), dim3(256), 0, stream,
                     x, WTh, WTm, Qhp, Qmp, Khp, Kmp, UTb);
  hipLaunchKernelGGL(attn_kernel, dim3(512), dim3(256), 0, stream,
                     Qhp, Qmp, Khp, Kmp, UTb, Pmp, Plp, Pyp);
  if (big_ws) {
    hipLaunchKernelGGL(out_fused_kernel, dim3(64, 8), dim3(256), 0, stream,
                       Pmp, Plp, Pyp, WvTh, WvTm, out);
  } else {
    ushort* Yhp = (ushort*)(wb + S_YH);
    ushort* Ymp = (ushort*)(wb + S_YM);
    hipLaunchKernelGGL(combine_kernel, dim3(1024), dim3(256), 0, stream,
                       Pmp, Plp, Pyp, Yhp, Ymp);
    hipLaunchKernelGGL(out_mfma_kernel, dim3(64, 8), dim3(256), 0, stream,
                       Yhp, Ymp, WvTh, WvTm, out);
  }
}